// Round 2
// baseline (451.150 us; speedup 1.0000x reference)
//
#include <hip/hip_runtime.h>
#include <hip/hip_bf16.h>
#include <hip/hip_fp16.h>
#include <stdint.h>

#define D_ 4
#define B_ 16384
#define H_ 1024

typedef __attribute__((ext_vector_type(8))) __bf16 bf16x8;
typedef __attribute__((ext_vector_type(8))) short short8;
typedef __attribute__((ext_vector_type(4))) float f32x4;

#define BM 128
#define BN 128
#define BK 64

typedef __attribute__((address_space(1))) void gvoid_t;
typedef __attribute__((address_space(3))) void lvoid_t;

__device__ __forceinline__ void async_copy16(const void* g, void* l) {
    // width=16 global->LDS DMA; LDS dest = wave-uniform base + lane*16
    __builtin_amdgcn_global_load_lds((const gvoid_t*)g, (lvoid_t*)l, 16, 0, 0);
}

__device__ __forceinline__ unsigned short f2b(float f) {  // fp32 -> bf16 bits, RNE
    union { float f; uint32_t i; } v; v.f = f;
    uint32_t r = v.i + 0x7fffu + ((v.i >> 16) & 1u);
    return (unsigned short)(r >> 16);
}

// ---------------- K0: feats fp32 -> bf16 (Xbf) ----------------
__global__ __launch_bounds__(256) void k0_cvt(const float* __restrict__ X,
                                              unsigned short* __restrict__ Xbf) {
    const size_t n8 = (size_t)D_ * B_ * H_ / 8;
    for (size_t p = (size_t)blockIdx.x * 256 + threadIdx.x; p < n8;
         p += (size_t)gridDim.x * 256) {
        f32x4 a = *(const f32x4*)(X + p * 8);
        f32x4 b = *(const f32x4*)(X + p * 8 + 4);
        short8 o;
        o[0] = (short)f2b(a[0]); o[1] = (short)f2b(a[1]);
        o[2] = (short)f2b(a[2]); o[3] = (short)f2b(a[3]);
        o[4] = (short)f2b(b[0]); o[5] = (short)f2b(b[1]);
        o[6] = (short)f2b(b[2]); o[7] = (short)f2b(b[3]);
        *(short8*)(Xbf + p * 8) = o;
    }
}

// ---------------- K1: T[d] = Xbf[d] @ W[d]^T  (bf16 MFMA, T stored fp16) ----------------
// A: bf16 from Xbf, DMA-staged, row=128B, read-swizzle ^((r&7)<<4)
// B: fp32 from weights, DMA-staged, row=256B, read-swizzle ^((r&15)<<4), in-frag cvt to bf16
__global__ __launch_bounds__(256) void k1_gemm(const unsigned short* __restrict__ Xbf,
                                               const float* __restrict__ W,
                                               unsigned short* __restrict__ T) {
    __shared__ __align__(16) unsigned short As[BM * BK];  // 16 KB
    __shared__ __align__(16) float Bs[BN * BK];           // 32 KB

    const int tid  = threadIdx.x;
    const int lane = tid & 63;
    const int w    = tid >> 6;

    // XCD-aware swizzle: 4096 tiles, 8 XCDs, 512 contiguous per XCD
    const int bid0 = blockIdx.x;
    const int bid  = (bid0 & 7) * 512 + (bid0 >> 3);
    const int d    = bid >> 10;
    const int t    = bid & 1023;
    const int tn   = t & 7;       // N/BN = 8
    const int tm   = t >> 3;      // M/BM = 128

    const size_t Xbase = ((size_t)d * B_ + (size_t)tm * BM) * H_;
    const size_t Wbase = ((size_t)d * H_ + (size_t)tn * BN) * H_;

    // A staging: linear LDS byte L = i*4096 + tid*16; row=L>>7 (128B rows);
    // content at swz slot L must be element col = ((L&127) ^ ((r&7)<<4))>>1
    int arow[4], acol[4];
#pragma unroll
    for (int i = 0; i < 4; ++i) {
        int L = i * 4096 + tid * 16;
        int r = L >> 7;
        arow[i] = r;
        acol[i] = ((L & 127) ^ ((r & 7) << 4)) >> 1;
    }
    // B staging: fp32 rows of 256B; col_float = ((L&255) ^ ((r&15)<<4))>>2
    int brow[8], bcol[8];
#pragma unroll
    for (int i = 0; i < 8; ++i) {
        int L = i * 4096 + tid * 16;
        int r = L >> 8;
        brow[i] = r;
        bcol[i] = ((L & 255) ^ ((r & 15) << 4)) >> 2;
    }

    f32x4 acc[4][4];
#pragma unroll
    for (int mi = 0; mi < 4; ++mi)
#pragma unroll
        for (int ni = 0; ni < 4; ++ni)
            acc[mi][ni] = (f32x4){0.f, 0.f, 0.f, 0.f};

    const int wr = w >> 1, wc = w & 1;

    for (int kt = 0; kt < H_ / BK; ++kt) {
        const int k0 = kt * BK;
#pragma unroll
        for (int i = 0; i < 4; ++i)
            async_copy16(Xbf + Xbase + (size_t)arow[i] * H_ + (k0 + acol[i]),
                         (char*)As + i * 4096 + w * 1024);
#pragma unroll
        for (int i = 0; i < 8; ++i)
            async_copy16(W + Wbase + (size_t)brow[i] * H_ + (k0 + bcol[i]),
                         (char*)Bs + i * 4096 + w * 1024);
        __syncthreads();  // compiler drains vmcnt before s_barrier

#pragma unroll
        for (int ks = 0; ks < 2; ++ks) {
            const int cba = ks * 64 + (lane >> 4) * 16;   // A col byte (bf16)
            const int cbb = ks * 128 + (lane >> 4) * 32;  // B col byte (fp32)
            bf16x8 af[4], bfr[4];
#pragma unroll
            for (int mi = 0; mi < 4; ++mi) {
                int r = wr * 64 + mi * 16 + (lane & 15);
                af[mi] = *(const bf16x8*)((const char*)As + (r << 7) + (cba ^ ((r & 7) << 4)));
            }
#pragma unroll
            for (int ni = 0; ni < 4; ++ni) {
                int r = wc * 64 + ni * 16 + (lane & 15);
                int sw = (r & 15) << 4;
                f32x4 lo = *(const f32x4*)((const char*)Bs + (r << 8) + (cbb ^ sw));
                f32x4 hi = *(const f32x4*)((const char*)Bs + (r << 8) + ((cbb + 16) ^ sw));
                bf16x8 bb;
                bb[0] = (__bf16)lo[0]; bb[1] = (__bf16)lo[1];
                bb[2] = (__bf16)lo[2]; bb[3] = (__bf16)lo[3];
                bb[4] = (__bf16)hi[0]; bb[5] = (__bf16)hi[1];
                bb[6] = (__bf16)hi[2]; bb[7] = (__bf16)hi[3];
                bfr[ni] = bb;
            }
#pragma unroll
            for (int mi = 0; mi < 4; ++mi)
#pragma unroll
                for (int ni = 0; ni < 4; ++ni)
                    acc[mi][ni] = __builtin_amdgcn_mfma_f32_16x16x32_bf16(af[mi], bfr[ni], acc[mi][ni], 0, 0, 0);
        }
        __syncthreads();
    }

    // C/D layout: col = lane&15, row = (lane>>4)*4 + j  [m89/m91]
    unsigned short* Td = T + (size_t)d * B_ * H_;
    const int row0 = tm * BM + wr * 64;
    const int col0 = tn * BN + wc * 64;
#pragma unroll
    for (int mi = 0; mi < 4; ++mi) {
#pragma unroll
        for (int j = 0; j < 4; ++j) {
            int r = row0 + mi * 16 + (lane >> 4) * 4 + j;
            unsigned short* dst = Td + (size_t)r * H_ + col0 + (lane & 15);
#pragma unroll
            for (int ni = 0; ni < 4; ++ni) {
                __half h = __float2half(acc[mi][ni][j]);
                dst[ni * 16] = *(unsigned short*)&h;
            }
        }
    }
}

// ---------------- K2: per-row norms + 10 pair dots on fp16 T ----------------
__global__ __launch_bounds__(256) void k2_scores(const unsigned short* __restrict__ T,
                                                 float* __restrict__ partials) {
    const int lane = threadIdx.x & 63;
    const int w    = threadIdx.x >> 6;
    const int gw   = blockIdx.x * 4 + w;  // 0..1023
    const size_t BH = (size_t)B_ * H_;

    float s[10];
#pragma unroll
    for (int p = 0; p < 10; ++p) s[p] = 0.f;

    for (int b = gw; b < B_; b += 1024) {
        const unsigned short* row = T + (size_t)b * H_;
        short8 u[4][2];
#pragma unroll
        for (int i = 0; i < 4; ++i) {
            u[i][0] = *(const short8*)(row + (size_t)i * BH + lane * 8);
            u[i][1] = *(const short8*)(row + (size_t)i * BH + 512 + lane * 8);
        }
        float dot[10];
#pragma unroll
        for (int p = 0; p < 10; ++p) dot[p] = 0.f;
#pragma unroll
        for (int h = 0; h < 2; ++h) {
#pragma unroll
            for (int e = 0; e < 8; ++e) {
                unsigned short b0 = (unsigned short)u[0][h][e];
                unsigned short b1 = (unsigned short)u[1][h][e];
                unsigned short b2 = (unsigned short)u[2][h][e];
                unsigned short b3 = (unsigned short)u[3][h][e];
                float f0 = __half2float(*(__half*)&b0);
                float f1 = __half2float(*(__half*)&b1);
                float f2v = __half2float(*(__half*)&b2);
                float f3 = __half2float(*(__half*)&b3);
                dot[0] += f0 * f0;  dot[1] += f0 * f1;  dot[2] += f0 * f2v; dot[3] += f0 * f3;
                dot[4] += f1 * f1;  dot[5] += f1 * f2v; dot[6] += f1 * f3;
                dot[7] += f2v * f2v; dot[8] += f2v * f3; dot[9] += f3 * f3;
            }
        }
#pragma unroll
        for (int p = 0; p < 10; ++p) {
            float v = dot[p];
#pragma unroll
            for (int m = 1; m < 64; m <<= 1) v += __shfl_xor(v, m, 64);
            dot[p] = v;
        }
        // guarded rsqrt: a wrong/zero GEMM gives finite wrong scores, not NaN
        float i0 = rsqrtf(fmaxf(dot[0], 1e-24f));
        float i1 = rsqrtf(fmaxf(dot[4], 1e-24f));
        float i2 = rsqrtf(fmaxf(dot[7], 1e-24f));
        float i3 = rsqrtf(fmaxf(dot[9], 1e-24f));
        s[0] += dot[0] * i0 * i0;  s[1] += dot[1] * i0 * i1;
        s[2] += dot[2] * i0 * i2;  s[3] += dot[3] * i0 * i3;
        s[4] += dot[4] * i1 * i1;  s[5] += dot[5] * i1 * i2;
        s[6] += dot[6] * i1 * i3;  s[7] += dot[7] * i2 * i2;
        s[8] += dot[8] * i2 * i3;  s[9] += dot[9] * i3 * i3;
    }
    __shared__ float red[4][10];
    if (lane == 0) {
#pragma unroll
        for (int p = 0; p < 10; ++p) red[w][p] = s[p];
    }
    __syncthreads();
    if (threadIdx.x < 10)
        partials[blockIdx.x * 10 + threadIdx.x] =
            red[0][threadIdx.x] + red[1][threadIdx.x] + red[2][threadIdx.x] + red[3][threadIdx.x];
}

// ---------------- K2b: reduce partials, softmax -> attn[16] ----------------
__global__ void k2b_reduce(const float* __restrict__ partials, float* __restrict__ attn) {
    __shared__ float sums[10];
    int t = threadIdx.x;  // 64 threads
    if (t < 10) {
        float v = 0.f;
        for (int i = 0; i < 256; ++i) v += partials[i * 10 + t];
        sums[t] = v;
    }
    __syncthreads();
    if (t == 0) {
        const int pidx[4][4] = {{0, 1, 2, 3}, {1, 4, 5, 6}, {2, 5, 7, 8}, {3, 6, 8, 9}};
        for (int i = 0; i < 4; ++i) {
            float sc[4], m = -1e30f;
            for (int j = 0; j < 4; ++j) {
                sc[j] = sums[pidx[i][j]] * (1.0f / (float)B_);
                m = fmaxf(m, sc[j]);
            }
            float sum = 0.f;
            for (int j = 0; j < 4; ++j) { sc[j] = expf(sc[j] - m); sum += sc[j]; }
            for (int j = 0; j < 4; ++j) attn[i * 4 + j] = sc[j] / sum;
        }
    }
}

// ---------------- K3: out[d] = sum_g attn[d][g] * feats[g]  (pure fp32) ----------------
__global__ __launch_bounds__(256) void k3_out(const float* __restrict__ X,
                                              const float* __restrict__ attn,
                                              float* __restrict__ out) {
    float a[16];
#pragma unroll
    for (int i = 0; i < 16; ++i) a[i] = attn[i];
    const size_t BH = (size_t)B_ * H_;
    const size_t nv = BH / 4;
    for (size_t p = (size_t)blockIdx.x * 256 + threadIdx.x; p < nv;
         p += (size_t)gridDim.x * 256) {
        f32x4 g0 = *(const f32x4*)(X + p * 4);
        f32x4 g1 = *(const f32x4*)(X + BH + p * 4);
        f32x4 g2 = *(const f32x4*)(X + 2 * BH + p * 4);
        f32x4 g3 = *(const f32x4*)(X + 3 * BH + p * 4);
        f32x4 o0, o1, o2, o3;
#pragma unroll
        for (int e = 0; e < 4; ++e) {
            o0[e] = a[0]  * g0[e] + a[1]  * g1[e] + a[2]  * g2[e] + a[3]  * g3[e];
            o1[e] = a[4]  * g0[e] + a[5]  * g1[e] + a[6]  * g2[e] + a[7]  * g3[e];
            o2[e] = a[8]  * g0[e] + a[9]  * g1[e] + a[10] * g2[e] + a[11] * g3[e];
            o3[e] = a[12] * g0[e] + a[13] * g1[e] + a[14] * g2[e] + a[15] * g3[e];
        }
        *(f32x4*)(out + p * 4) = o0;
        *(f32x4*)(out + BH + p * 4) = o1;
        *(f32x4*)(out + 2 * BH + p * 4) = o2;
        *(f32x4*)(out + 3 * BH + p * 4) = o3;
    }
}

extern "C" void kernel_launch(void* const* d_in, const int* in_sizes, int n_in,
                              void* d_out, int out_size, void* d_ws, size_t ws_size,
                              hipStream_t stream) {
    (void)in_sizes; (void)n_in; (void)out_size; (void)ws_size;
    const float* feats   = (const float*)d_in[0];   // fp32 [4][16384][1024]
    const float* weights = (const float*)d_in[1];   // fp32 [4][1024][1024]
    float* out = (float*)d_out;

    // d_out layout during pipeline: [T fp16: 134.2MB][Xbf bf16: 134.2MB] = exactly out bytes
    const size_t half_bytes = (size_t)D_ * B_ * H_ * 2;
    unsigned short* T   = (unsigned short*)d_out;
    unsigned short* Xbf = (unsigned short*)((char*)d_out + half_bytes);

    float* attn     = (float*)d_ws;                      // 16 floats
    float* partials = (float*)((char*)d_ws + 256);       // 256*10 floats = 10 KB

    k0_cvt<<<2048, 256, 0, stream>>>(feats, Xbf);
    k1_gemm<<<4096, 256, 0, stream>>>(Xbf, weights, T);
    k2_scores<<<256, 256, 0, stream>>>(T, partials);
    k2b_reduce<<<1, 64, 0, stream>>>(partials, attn);
    k3_out<<<2048, 256, 0, stream>>>(feats, attn, out);
}

// Round 3
// 429.828 us; speedup vs baseline: 1.0496x; 1.0496x over previous
//
#include <hip/hip_runtime.h>
#include <hip/hip_bf16.h>
#include <hip/hip_fp16.h>
#include <stdint.h>

#define D_ 4
#define B_ 16384
#define H_ 1024

typedef __attribute__((ext_vector_type(8))) __bf16 bf16x8;
typedef __attribute__((ext_vector_type(8))) short short8;
typedef __attribute__((ext_vector_type(4))) float f32x4;

#define BM 128
#define BN 128
#define BK 64

typedef __attribute__((address_space(1))) void gvoid_t;
typedef __attribute__((address_space(3))) void lvoid_t;

__device__ __forceinline__ void async_copy16(const void* g, void* l) {
    // width=16 global->LDS DMA; LDS dest = wave-uniform base + lane*16
    __builtin_amdgcn_global_load_lds((const gvoid_t*)g, (lvoid_t*)l, 16, 0, 0);
}

__device__ __forceinline__ unsigned short f2b(float f) {  // fp32 -> bf16 bits, RNE
    union { float f; uint32_t i; } v; v.f = f;
    uint32_t r = v.i + 0x7fffu + ((v.i >> 16) & 1u);
    return (unsigned short)(r >> 16);
}

// ---------------- K0: feats fp32 -> bf16 (Xbf) ----------------
__global__ __launch_bounds__(256) void k0_cvt(const float* __restrict__ X,
                                              unsigned short* __restrict__ Xbf) {
    const size_t n8 = (size_t)D_ * B_ * H_ / 8;
    for (size_t p = (size_t)blockIdx.x * 256 + threadIdx.x; p < n8;
         p += (size_t)gridDim.x * 256) {
        f32x4 a = *(const f32x4*)(X + p * 8);
        f32x4 b = *(const f32x4*)(X + p * 8 + 4);
        short8 o;
        o[0] = (short)f2b(a[0]); o[1] = (short)f2b(a[1]);
        o[2] = (short)f2b(a[2]); o[3] = (short)f2b(a[3]);
        o[4] = (short)f2b(b[0]); o[5] = (short)f2b(b[1]);
        o[6] = (short)f2b(b[2]); o[7] = (short)f2b(b[3]);
        *(short8*)(Xbf + p * 8) = o;
    }
}

// ---------------- K0b: weights fp32 -> bf16 (Wbf, 8.4 MB in ws) ----------------
__global__ __launch_bounds__(256) void k0b_cvt(const float* __restrict__ W,
                                               unsigned short* __restrict__ Wbf) {
    const size_t n8 = (size_t)D_ * H_ * H_ / 8;
    for (size_t p = (size_t)blockIdx.x * 256 + threadIdx.x; p < n8;
         p += (size_t)gridDim.x * 256) {
        f32x4 a = *(const f32x4*)(W + p * 8);
        f32x4 b = *(const f32x4*)(W + p * 8 + 4);
        short8 o;
        o[0] = (short)f2b(a[0]); o[1] = (short)f2b(a[1]);
        o[2] = (short)f2b(a[2]); o[3] = (short)f2b(a[3]);
        o[4] = (short)f2b(b[0]); o[5] = (short)f2b(b[1]);
        o[6] = (short)f2b(b[2]); o[7] = (short)f2b(b[3]);
        *(short8*)(Wbf + p * 8) = o;
    }
}

// ---------------- K1 (primary): T = Xbf @ Wbf^T, both operands bf16 (m97 structure) ----------------
// 128x128x64 tile, 4 waves 2x2, 4x4 frags, global_load_lds w=16, st-XOR swizzle both sides.
__global__ __launch_bounds__(256) void k1_gemm_bf(const unsigned short* __restrict__ Xbf,
                                                  const unsigned short* __restrict__ Wbf,
                                                  unsigned short* __restrict__ T) {
    __shared__ __align__(16) unsigned short As[BM * BK];  // 16 KB
    __shared__ __align__(16) unsigned short Bs[BN * BK];  // 16 KB

    const int tid  = threadIdx.x;
    const int lane = tid & 63;
    const int w    = tid >> 6;

    // XCD-aware swizzle: 4096 tiles, 8 XCDs, 512 contiguous per XCD
    const int bid0 = blockIdx.x;
    const int bid  = (bid0 & 7) * 512 + (bid0 >> 3);
    const int d    = bid >> 10;
    const int t    = bid & 1023;
    const int tn   = t & 7;       // N/BN = 8
    const int tm   = t >> 3;      // M/BM = 128

    const size_t Xbase = ((size_t)d * B_ + (size_t)tm * BM) * H_;
    const size_t Wbase = ((size_t)d * H_ + (size_t)tn * BN) * H_;

    // Staging: linear LDS byte L = i*4096 + tid*16; 128B rows; swizzled-source col
    int srow[4], scol[4];
#pragma unroll
    for (int i = 0; i < 4; ++i) {
        int L = i * 4096 + tid * 16;
        int r = L >> 7;
        srow[i] = r;
        scol[i] = ((L & 127) ^ ((r & 7) << 4)) >> 1;
    }

    f32x4 acc[4][4];
#pragma unroll
    for (int mi = 0; mi < 4; ++mi)
#pragma unroll
        for (int ni = 0; ni < 4; ++ni)
            acc[mi][ni] = (f32x4){0.f, 0.f, 0.f, 0.f};

    const int wr = w >> 1, wc = w & 1;

    for (int kt = 0; kt < H_ / BK; ++kt) {
        const int k0 = kt * BK;
#pragma unroll
        for (int i = 0; i < 4; ++i) {
            async_copy16(Xbf + Xbase + (size_t)srow[i] * H_ + (k0 + scol[i]),
                         (char*)As + i * 4096 + w * 1024);
            async_copy16(Wbf + Wbase + (size_t)srow[i] * H_ + (k0 + scol[i]),
                         (char*)Bs + i * 4096 + w * 1024);
        }
        __syncthreads();  // compiler drains vmcnt before s_barrier

#pragma unroll
        for (int ks = 0; ks < 2; ++ks) {
            const int cb = ks * 64 + (lane >> 4) * 16;  // col byte offset (bf16)
            bf16x8 af[4], bfr[4];
#pragma unroll
            for (int mi = 0; mi < 4; ++mi) {
                int r = wr * 64 + mi * 16 + (lane & 15);
                af[mi] = *(const bf16x8*)((const char*)As + (r << 7) + (cb ^ ((r & 7) << 4)));
            }
#pragma unroll
            for (int ni = 0; ni < 4; ++ni) {
                int r = wc * 64 + ni * 16 + (lane & 15);
                bfr[ni] = *(const bf16x8*)((const char*)Bs + (r << 7) + (cb ^ ((r & 7) << 4)));
            }
#pragma unroll
            for (int mi = 0; mi < 4; ++mi)
#pragma unroll
                for (int ni = 0; ni < 4; ++ni)
                    acc[mi][ni] = __builtin_amdgcn_mfma_f32_16x16x32_bf16(af[mi], bfr[ni], acc[mi][ni], 0, 0, 0);
        }
        __syncthreads();
    }

    // C/D layout: col = lane&15, row = (lane>>4)*4 + j  [m89/m91]
    unsigned short* Td = T + (size_t)d * B_ * H_;
    const int row0 = tm * BM + wr * 64;
    const int col0 = tn * BN + wc * 64;
#pragma unroll
    for (int mi = 0; mi < 4; ++mi) {
#pragma unroll
        for (int j = 0; j < 4; ++j) {
            int r = row0 + mi * 16 + (lane >> 4) * 4 + j;
            unsigned short* dst = Td + (size_t)r * H_ + col0 + (lane & 15);
#pragma unroll
            for (int ni = 0; ni < 4; ++ni) {
                __half h = __float2half(acc[mi][ni][j]);
                dst[ni * 16] = *(unsigned short*)&h;
            }
        }
    }
}

// ---------------- K1 (fallback, proven): B staged fp32 with in-frag cvt ----------------
__global__ __launch_bounds__(256) void k1_gemm(const unsigned short* __restrict__ Xbf,
                                               const float* __restrict__ W,
                                               unsigned short* __restrict__ T) {
    __shared__ __align__(16) unsigned short As[BM * BK];  // 16 KB
    __shared__ __align__(16) float Bs[BN * BK];           // 32 KB

    const int tid  = threadIdx.x;
    const int lane = tid & 63;
    const int w    = tid >> 6;

    const int bid0 = blockIdx.x;
    const int bid  = (bid0 & 7) * 512 + (bid0 >> 3);
    const int d    = bid >> 10;
    const int t    = bid & 1023;
    const int tn   = t & 7;
    const int tm   = t >> 3;

    const size_t Xbase = ((size_t)d * B_ + (size_t)tm * BM) * H_;
    const size_t Wbase = ((size_t)d * H_ + (size_t)tn * BN) * H_;

    int arow[4], acol[4];
#pragma unroll
    for (int i = 0; i < 4; ++i) {
        int L = i * 4096 + tid * 16;
        int r = L >> 7;
        arow[i] = r;
        acol[i] = ((L & 127) ^ ((r & 7) << 4)) >> 1;
    }
    int brow[8], bcol[8];
#pragma unroll
    for (int i = 0; i < 8; ++i) {
        int L = i * 4096 + tid * 16;
        int r = L >> 8;
        brow[i] = r;
        bcol[i] = ((L & 255) ^ ((r & 15) << 4)) >> 2;
    }

    f32x4 acc[4][4];
#pragma unroll
    for (int mi = 0; mi < 4; ++mi)
#pragma unroll
        for (int ni = 0; ni < 4; ++ni)
            acc[mi][ni] = (f32x4){0.f, 0.f, 0.f, 0.f};

    const int wr = w >> 1, wc = w & 1;

    for (int kt = 0; kt < H_ / BK; ++kt) {
        const int k0 = kt * BK;
#pragma unroll
        for (int i = 0; i < 4; ++i)
            async_copy16(Xbf + Xbase + (size_t)arow[i] * H_ + (k0 + acol[i]),
                         (char*)As + i * 4096 + w * 1024);
#pragma unroll
        for (int i = 0; i < 8; ++i)
            async_copy16(W + Wbase + (size_t)brow[i] * H_ + (k0 + bcol[i]),
                         (char*)Bs + i * 4096 + w * 1024);
        __syncthreads();

#pragma unroll
        for (int ks = 0; ks < 2; ++ks) {
            const int cba = ks * 64 + (lane >> 4) * 16;
            const int cbb = ks * 128 + (lane >> 4) * 32;
            bf16x8 af[4], bfr[4];
#pragma unroll
            for (int mi = 0; mi < 4; ++mi) {
                int r = wr * 64 + mi * 16 + (lane & 15);
                af[mi] = *(const bf16x8*)((const char*)As + (r << 7) + (cba ^ ((r & 7) << 4)));
            }
#pragma unroll
            for (int ni = 0; ni < 4; ++ni) {
                int r = wc * 64 + ni * 16 + (lane & 15);
                int sw = (r & 15) << 4;
                f32x4 lo = *(const f32x4*)((const char*)Bs + (r << 8) + (cbb ^ sw));
                f32x4 hi = *(const f32x4*)((const char*)Bs + (r << 8) + ((cbb + 16) ^ sw));
                bf16x8 bb;
                bb[0] = (__bf16)lo[0]; bb[1] = (__bf16)lo[1];
                bb[2] = (__bf16)lo[2]; bb[3] = (__bf16)lo[3];
                bb[4] = (__bf16)hi[0]; bb[5] = (__bf16)hi[1];
                bb[6] = (__bf16)hi[2]; bb[7] = (__bf16)hi[3];
                bfr[ni] = bb;
            }
#pragma unroll
            for (int mi = 0; mi < 4; ++mi)
#pragma unroll
                for (int ni = 0; ni < 4; ++ni)
                    acc[mi][ni] = __builtin_amdgcn_mfma_f32_16x16x32_bf16(af[mi], bfr[ni], acc[mi][ni], 0, 0, 0);
        }
        __syncthreads();
    }

    unsigned short* Td = T + (size_t)d * B_ * H_;
    const int row0 = tm * BM + wr * 64;
    const int col0 = tn * BN + wc * 64;
#pragma unroll
    for (int mi = 0; mi < 4; ++mi) {
#pragma unroll
        for (int j = 0; j < 4; ++j) {
            int r = row0 + mi * 16 + (lane >> 4) * 4 + j;
            unsigned short* dst = Td + (size_t)r * H_ + col0 + (lane & 15);
#pragma unroll
            for (int ni = 0; ni < 4; ++ni) {
                __half h = __float2half(acc[mi][ni][j]);
                dst[ni * 16] = *(unsigned short*)&h;
            }
        }
    }
}

// ---------------- K2: per-row norms + 10 pair dots on fp16 T ----------------
__global__ __launch_bounds__(256) void k2_scores(const unsigned short* __restrict__ T,
                                                 float* __restrict__ partials) {
    const int lane = threadIdx.x & 63;
    const int w    = threadIdx.x >> 6;
    const int gw   = blockIdx.x * 4 + w;  // 0..1023
    const size_t BH = (size_t)B_ * H_;

    float s[10];
#pragma unroll
    for (int p = 0; p < 10; ++p) s[p] = 0.f;

    for (int b = gw; b < B_; b += 1024) {
        const unsigned short* row = T + (size_t)b * H_;
        short8 u[4][2];
#pragma unroll
        for (int i = 0; i < 4; ++i) {
            u[i][0] = *(const short8*)(row + (size_t)i * BH + lane * 8);
            u[i][1] = *(const short8*)(row + (size_t)i * BH + 512 + lane * 8);
        }
        float dot[10];
#pragma unroll
        for (int p = 0; p < 10; ++p) dot[p] = 0.f;
#pragma unroll
        for (int h = 0; h < 2; ++h) {
#pragma unroll
            for (int e = 0; e < 8; ++e) {
                unsigned short b0 = (unsigned short)u[0][h][e];
                unsigned short b1 = (unsigned short)u[1][h][e];
                unsigned short b2 = (unsigned short)u[2][h][e];
                unsigned short b3 = (unsigned short)u[3][h][e];
                float f0 = __half2float(*(__half*)&b0);
                float f1 = __half2float(*(__half*)&b1);
                float f2v = __half2float(*(__half*)&b2);
                float f3 = __half2float(*(__half*)&b3);
                dot[0] += f0 * f0;  dot[1] += f0 * f1;  dot[2] += f0 * f2v; dot[3] += f0 * f3;
                dot[4] += f1 * f1;  dot[5] += f1 * f2v; dot[6] += f1 * f3;
                dot[7] += f2v * f2v; dot[8] += f2v * f3; dot[9] += f3 * f3;
            }
        }
#pragma unroll
        for (int p = 0; p < 10; ++p) {
            float v = dot[p];
#pragma unroll
            for (int m = 1; m < 64; m <<= 1) v += __shfl_xor(v, m, 64);
            dot[p] = v;
        }
        float i0 = rsqrtf(fmaxf(dot[0], 1e-24f));
        float i1 = rsqrtf(fmaxf(dot[4], 1e-24f));
        float i2 = rsqrtf(fmaxf(dot[7], 1e-24f));
        float i3 = rsqrtf(fmaxf(dot[9], 1e-24f));
        s[0] += dot[0] * i0 * i0;  s[1] += dot[1] * i0 * i1;
        s[2] += dot[2] * i0 * i2;  s[3] += dot[3] * i0 * i3;
        s[4] += dot[4] * i1 * i1;  s[5] += dot[5] * i1 * i2;
        s[6] += dot[6] * i1 * i3;  s[7] += dot[7] * i2 * i2;
        s[8] += dot[8] * i2 * i3;  s[9] += dot[9] * i3 * i3;
    }
    __shared__ float red[4][10];
    if (lane == 0) {
#pragma unroll
        for (int p = 0; p < 10; ++p) red[w][p] = s[p];
    }
    __syncthreads();
    if (threadIdx.x < 10)
        partials[blockIdx.x * 10 + threadIdx.x] =
            red[0][threadIdx.x] + red[1][threadIdx.x] + red[2][threadIdx.x] + red[3][threadIdx.x];
}

// ---------------- K2b: reduce partials, softmax -> attn[16] ----------------
__global__ void k2b_reduce(const float* __restrict__ partials, float* __restrict__ attn) {
    __shared__ float sums[10];
    int t = threadIdx.x;  // 64 threads
    if (t < 10) {
        float v = 0.f;
        for (int i = 0; i < 256; ++i) v += partials[i * 10 + t];
        sums[t] = v;
    }
    __syncthreads();
    if (t == 0) {
        const int pidx[4][4] = {{0, 1, 2, 3}, {1, 4, 5, 6}, {2, 5, 7, 8}, {3, 6, 8, 9}};
        for (int i = 0; i < 4; ++i) {
            float sc[4], m = -1e30f;
            for (int j = 0; j < 4; ++j) {
                sc[j] = sums[pidx[i][j]] * (1.0f / (float)B_);
                m = fmaxf(m, sc[j]);
            }
            float sum = 0.f;
            for (int j = 0; j < 4; ++j) { sc[j] = expf(sc[j] - m); sum += sc[j]; }
            for (int j = 0; j < 4; ++j) attn[i * 4 + j] = sc[j] / sum;
        }
    }
}

// ---------------- K3: out[d] = sum_g attn[d][g] * feats[g]  (pure fp32) ----------------
__global__ __launch_bounds__(256) void k3_out(const float* __restrict__ X,
                                              const float* __restrict__ attn,
                                              float* __restrict__ out) {
    float a[16];
#pragma unroll
    for (int i = 0; i < 16; ++i) a[i] = attn[i];
    const size_t BH = (size_t)B_ * H_;
    const size_t nv = BH / 4;
    for (size_t p = (size_t)blockIdx.x * 256 + threadIdx.x; p < nv;
         p += (size_t)gridDim.x * 256) {
        f32x4 g0 = *(const f32x4*)(X + p * 4);
        f32x4 g1 = *(const f32x4*)(X + BH + p * 4);
        f32x4 g2 = *(const f32x4*)(X + 2 * BH + p * 4);
        f32x4 g3 = *(const f32x4*)(X + 3 * BH + p * 4);
        f32x4 o0, o1, o2, o3;
#pragma unroll
        for (int e = 0; e < 4; ++e) {
            o0[e] = a[0]  * g0[e] + a[1]  * g1[e] + a[2]  * g2[e] + a[3]  * g3[e];
            o1[e] = a[4]  * g0[e] + a[5]  * g1[e] + a[6]  * g2[e] + a[7]  * g3[e];
            o2[e] = a[8]  * g0[e] + a[9]  * g1[e] + a[10] * g2[e] + a[11] * g3[e];
            o3[e] = a[12] * g0[e] + a[13] * g1[e] + a[14] * g2[e] + a[15] * g3[e];
        }
        *(f32x4*)(out + p * 4) = o0;
        *(f32x4*)(out + BH + p * 4) = o1;
        *(f32x4*)(out + 2 * BH + p * 4) = o2;
        *(f32x4*)(out + 3 * BH + p * 4) = o3;
    }
}

extern "C" void kernel_launch(void* const* d_in, const int* in_sizes, int n_in,
                              void* d_out, int out_size, void* d_ws, size_t ws_size,
                              hipStream_t stream) {
    (void)in_sizes; (void)n_in; (void)out_size;
    const float* feats   = (const float*)d_in[0];   // fp32 [4][16384][1024]
    const float* weights = (const float*)d_in[1];   // fp32 [4][1024][1024]
    float* out = (float*)d_out;

    // d_out during pipeline: [T fp16: 134.2MB][Xbf bf16: 134.2MB]
    const size_t half_bytes = (size_t)D_ * B_ * H_ * 2;
    unsigned short* T   = (unsigned short*)d_out;
    unsigned short* Xbf = (unsigned short*)((char*)d_out + half_bytes);

    float* attn     = (float*)d_ws;                      // 16 floats @ 0
    float* partials = (float*)((char*)d_ws + 256);       // 256*10 floats
    const size_t WBF_OFF   = 65536;
    const size_t WBF_BYTES = (size_t)D_ * H_ * H_ * 2;   // 8.39 MB
    unsigned short* Wbf = (unsigned short*)((char*)d_ws + WBF_OFF);
    const bool use_ws = ws_size >= WBF_OFF + WBF_BYTES;  // ws_size is fixed -> deterministic

    k0_cvt<<<2048, 256, 0, stream>>>(feats, Xbf);
    if (use_ws) {
        k0b_cvt<<<512, 256, 0, stream>>>(weights, Wbf);
        k1_gemm_bf<<<4096, 256, 0, stream>>>(Xbf, Wbf, T);
    } else {
        k1_gemm<<<4096, 256, 0, stream>>>(Xbf, weights, T);
    }
    k2_scores<<<256, 256, 0, stream>>>(T, partials);
    k2b_reduce<<<1, 64, 0, stream>>>(partials, attn);
    k3_out<<<2048, 256, 0, stream>>>(feats, attn, out);
}

// Round 4
// 352.437 us; speedup vs baseline: 1.2801x; 1.2196x over previous
//
#include <hip/hip_runtime.h>
#include <hip/hip_bf16.h>
#include <hip/hip_fp16.h>
#include <stdint.h>

#define D_ 4
#define B_ 16384
#define H_ 1024

typedef __attribute__((ext_vector_type(8))) __bf16 bf16x8;
typedef __attribute__((ext_vector_type(8))) short short8;
typedef __attribute__((ext_vector_type(4))) float f32x4;

typedef __attribute__((address_space(1))) void gvoid_t;
typedef __attribute__((address_space(3))) void lvoid_t;

__device__ __forceinline__ void async_copy16(const void* g, void* l) {
    // width=16 global->LDS DMA; LDS dest = wave-uniform base + lane*16
    __builtin_amdgcn_global_load_lds((const gvoid_t*)g, (lvoid_t*)l, 16, 0, 0);
}

__device__ __forceinline__ unsigned short f2b(float f) {  // fp32 -> bf16 bits, RNE
    union { float f; uint32_t i; } v; v.f = f;
    uint32_t r = v.i + 0x7fffu + ((v.i >> 16) & 1u);
    return (unsigned short)(r >> 16);
}

// ---------------- K0: feats fp32 -> bf16 (Xbf) ----------------
__global__ __launch_bounds__(256) void k0_cvt(const float* __restrict__ X,
                                              unsigned short* __restrict__ Xbf) {
    const size_t n8 = (size_t)D_ * B_ * H_ / 8;
    for (size_t p = (size_t)blockIdx.x * 256 + threadIdx.x; p < n8;
         p += (size_t)gridDim.x * 256) {
        f32x4 a = *(const f32x4*)(X + p * 8);
        f32x4 b = *(const f32x4*)(X + p * 8 + 4);
        short8 o;
        o[0] = (short)f2b(a[0]); o[1] = (short)f2b(a[1]);
        o[2] = (short)f2b(a[2]); o[3] = (short)f2b(a[3]);
        o[4] = (short)f2b(b[0]); o[5] = (short)f2b(b[1]);
        o[6] = (short)f2b(b[2]); o[7] = (short)f2b(b[3]);
        *(short8*)(Xbf + p * 8) = o;
    }
}

// ---------------- K0b: weights fp32 -> bf16 (Wbf in ws) ----------------
__global__ __launch_bounds__(256) void k0b_cvt(const float* __restrict__ W,
                                               unsigned short* __restrict__ Wbf) {
    const size_t n8 = (size_t)D_ * H_ * H_ / 8;
    for (size_t p = (size_t)blockIdx.x * 256 + threadIdx.x; p < n8;
         p += (size_t)gridDim.x * 256) {
        f32x4 a = *(const f32x4*)(W + p * 8);
        f32x4 b = *(const f32x4*)(W + p * 8 + 4);
        short8 o;
        o[0] = (short)f2b(a[0]); o[1] = (short)f2b(a[1]);
        o[2] = (short)f2b(a[2]); o[3] = (short)f2b(a[3]);
        o[4] = (short)f2b(b[0]); o[5] = (short)f2b(b[1]);
        o[6] = (short)f2b(b[2]); o[7] = (short)f2b(b[3]);
        *(short8*)(Wbf + p * 8) = o;
    }
}

// ============ K1 (primary): 256x256x64 8-phase double-buffered bf16 GEMM ============
// 8 waves (2M x 4N), per-wave 128x64 output = acc[8][4] f32x4.
// LDS 128KB: lds[buf*2+op][256*64] bf16, rows 128B, XOR swizzle byte ^= ((row&7)<<4).
// Counted vmcnt(4) at phases 1 and 5 only; raw s_barrier (no vmcnt drain).
__global__ __launch_bounds__(512, 2) void k1_gemm8(const unsigned short* __restrict__ Xbf,
                                                   const unsigned short* __restrict__ Wbf,
                                                   unsigned short* __restrict__ T) {
    __shared__ __align__(16) unsigned short lds[4][256 * 64];  // 128 KB

    const int tid  = threadIdx.x;
    const int lane = tid & 63;
    const int w    = tid >> 6;   // 0..7
    const int wr   = w >> 2;     // 0..1  (M half)
    const int wc   = w & 3;      // 0..3  (N quarter)

    // XCD-aware bijective swizzle: 1024 blocks, 128 per XCD
    const int bid0 = blockIdx.x;
    const int bid  = (bid0 & 7) * 128 + (bid0 >> 3);
    const int d    = bid >> 8;
    const int t    = bid & 255;
    const int tn   = t & 3;      // N/256 = 4
    const int tm   = t >> 2;     // M/256 = 64

    const size_t Xbase = ((size_t)d * B_ + (size_t)tm * 256) * H_;
    const size_t Wbase = ((size_t)d * H_ + (size_t)tn * 256) * H_;

    // Staging source precompute (pre-swizzled global source, linear LDS dest):
    // L = h*16384 + c*8192 + tid*16; row = L>>7; col = ((L&127) ^ ((row&7)<<4))>>1
    const unsigned short* aSrc[2][2];
    const unsigned short* bSrc[2][2];
#pragma unroll
    for (int h = 0; h < 2; ++h)
#pragma unroll
        for (int c = 0; c < 2; ++c) {
            int L = h * 16384 + c * 8192 + tid * 16;
            int r = L >> 7;
            int col = ((L & 127) ^ ((r & 7) << 4)) >> 1;
            aSrc[h][c] = Xbf + Xbase + (size_t)r * H_ + col;
            bSrc[h][c] = Wbf + Wbase + (size_t)r * H_ + col;
        }

    char* ldsB = (char*)&lds[0][0];

    auto stageA = [&](int buf, int h, int kt) {
#pragma unroll
        for (int c = 0; c < 2; ++c)
            async_copy16(aSrc[h][c] + kt * 64,
                         ldsB + (buf * 2 + 0) * 32768 + h * 16384 + c * 8192 + w * 1024);
    };
    auto stageB = [&](int buf, int h, int kt) {
#pragma unroll
        for (int c = 0; c < 2; ++c)
            async_copy16(bSrc[h][c] + kt * 64,
                         ldsB + (buf * 2 + 1) * 32768 + h * 16384 + c * 8192 + w * 1024);
    };

    bf16x8 ar[4][2], b0[2][2], b1[2][2];
    const int rA15 = lane & 15;
    const int cB16 = (lane >> 4) * 16;

    auto readA = [&](int buf, int mib) {
#pragma unroll
        for (int mi = 0; mi < 4; ++mi) {
            int r = wr * 128 + mib + mi * 16 + rA15;
            const char* base = ldsB + (buf * 2 + 0) * 32768 + (r << 7);
            int sw = (r & 7) << 4;
#pragma unroll
            for (int ks = 0; ks < 2; ++ks)
                ar[mi][ks] = *(const bf16x8*)(base + ((ks * 64 + cB16) ^ sw));
        }
    };
    auto readB0 = [&](int buf) {
#pragma unroll
        for (int ni = 0; ni < 2; ++ni) {
            int r = wc * 64 + ni * 16 + rA15;
            const char* base = ldsB + (buf * 2 + 1) * 32768 + (r << 7);
            int sw = (r & 7) << 4;
#pragma unroll
            for (int ks = 0; ks < 2; ++ks)
                b0[ni][ks] = *(const bf16x8*)(base + ((ks * 64 + cB16) ^ sw));
        }
    };
    auto readB1 = [&](int buf) {
#pragma unroll
        for (int ni = 0; ni < 2; ++ni) {
            int r = wc * 64 + 32 + ni * 16 + rA15;
            const char* base = ldsB + (buf * 2 + 1) * 32768 + (r << 7);
            int sw = (r & 7) << 4;
#pragma unroll
            for (int ks = 0; ks < 2; ++ks)
                b1[ni][ks] = *(const bf16x8*)(base + ((ks * 64 + cB16) ^ sw));
        }
    };

    f32x4 acc[8][4];
#pragma unroll
    for (int a = 0; a < 8; ++a)
#pragma unroll
        for (int n = 0; n < 4; ++n) acc[a][n] = (f32x4){0.f, 0.f, 0.f, 0.f};

#define VMCNT4 do { asm volatile("s_waitcnt vmcnt(4)" ::: "memory"); \
                    __builtin_amdgcn_sched_barrier(0); } while (0)
#define LGKM0  do { asm volatile("s_waitcnt lgkmcnt(0)" ::: "memory"); \
                    __builtin_amdgcn_sched_barrier(0); } while (0)
#define BAR    __builtin_amdgcn_s_barrier()

// 16 MFMAs: one 64x32 quadrant x K=64.  AOFF = 0|4 (acc row-frag base), B = b0|b1, NOFF = 0|2
#define MFMA16(AOFF, BB, NOFF)                                                              \
    do {                                                                                    \
        __builtin_amdgcn_s_setprio(1);                                                      \
        _Pragma("unroll")                                                                   \
        for (int ks = 0; ks < 2; ++ks)                                                      \
            _Pragma("unroll")                                                               \
            for (int mi = 0; mi < 4; ++mi)                                                  \
                _Pragma("unroll")                                                           \
                for (int ni = 0; ni < 2; ++ni)                                              \
                    acc[(AOFF) + mi][(NOFF) + ni] = __builtin_amdgcn_mfma_f32_16x16x32_bf16( \
                        ar[mi][ks], ((BB)[ni][ks]), acc[(AOFF) + mi][(NOFF) + ni], 0, 0, 0); \
        __builtin_amdgcn_s_setprio(0);                                                      \
    } while (0)

    // Prologue: buf0 <- K-tile 0 (A h0,h1 + B h0,h1); buf1 <- K-tile 1 (B h0,h1). 12 loads.
    stageA(0, 0, 0); stageA(0, 1, 0); stageB(0, 0, 0); stageB(0, 1, 0);
    stageB(1, 0, 1); stageB(1, 1, 1);

    for (int it = 0; it < 8; ++it) {
        const int ka  = 2 * it + 1;         // A for buf1, used phases 5-8 this iter
        const int kb2 = (2 * it + 2) & 15;  // -> buf0 (wraps harmlessly on last iter)
        const int kb3 = (2 * it + 3) & 15;  // -> buf1 (wraps harmlessly on last iter)

        // P1: q(r0,c0) buf0
        VMCNT4;
        readA(0, 0); readB0(0);
        stageA(1, 0, ka);
        BAR; LGKM0;
        MFMA16(0, b0, 0);
        BAR;
        // P2: q(r0,c1) buf0
        readB1(0);
        stageA(1, 1, ka);
        BAR; LGKM0;
        MFMA16(0, b1, 2);
        BAR;
        // P3: q(r1,c1) buf0
        readA(0, 64);
        stageB(0, 0, kb2);
        BAR; LGKM0;
        MFMA16(4, b1, 2);
        BAR;
        // P4: q(r1,c0) buf0 (no reads; b0 kept)
        stageB(0, 1, kb2);
        BAR; LGKM0;
        MFMA16(4, b0, 0);
        BAR;
        // P5: q(r0,c0) buf1
        VMCNT4;
        readA(1, 0); readB0(1);
        stageA(0, 0, kb2);
        BAR; LGKM0;
        MFMA16(0, b0, 0);
        BAR;
        // P6: q(r0,c1) buf1
        readB1(1);
        stageA(0, 1, kb2);
        BAR; LGKM0;
        MFMA16(0, b1, 2);
        BAR;
        // P7: q(r1,c1) buf1
        readA(1, 64);
        stageB(1, 0, kb3);
        BAR; LGKM0;
        MFMA16(4, b1, 2);
        BAR;
        // P8: q(r1,c0) buf1
        stageB(1, 1, kb3);
        BAR; LGKM0;
        MFMA16(4, b0, 0);
        BAR;
    }

#undef VMCNT4
#undef LGKM0
#undef BAR
#undef MFMA16

    // Epilogue: C/D frag layout col=lane&15, row=(lane>>4)*4+j; T stored fp16
    unsigned short* Td = T + (size_t)d * B_ * H_;
    const int row0 = tm * 256 + wr * 128;
    const int col0 = tn * 256 + wc * 64 + (lane & 15);
#pragma unroll
    for (int a = 0; a < 8; ++a) {
#pragma unroll
        for (int j = 0; j < 4; ++j) {
            int r = row0 + a * 16 + (lane >> 4) * 4 + j;
            unsigned short* dst = Td + (size_t)r * H_ + col0;
#pragma unroll
            for (int ni = 0; ni < 4; ++ni) {
                __half h = __float2half(acc[a][ni][j]);
                dst[ni * 16] = *(unsigned short*)&h;
            }
        }
    }
}

// ---------------- K1 (fallback, proven m97-style): only if ws too small ----------------
__global__ __launch_bounds__(256) void k1_gemm_bf(const unsigned short* __restrict__ Xbf,
                                                  const unsigned short* __restrict__ Wbf,
                                                  unsigned short* __restrict__ T) {
    __shared__ __align__(16) unsigned short As[128 * 64];
    __shared__ __align__(16) unsigned short Bs[128 * 64];

    const int tid  = threadIdx.x;
    const int lane = tid & 63;
    const int w    = tid >> 6;

    const int bid0 = blockIdx.x;
    const int bid  = (bid0 & 7) * 512 + (bid0 >> 3);
    const int d    = bid >> 10;
    const int t    = bid & 1023;
    const int tn   = t & 7;
    const int tm   = t >> 3;

    const size_t Xbase = ((size_t)d * B_ + (size_t)tm * 128) * H_;
    const size_t Wbase = ((size_t)d * H_ + (size_t)tn * 128) * H_;

    int srow[4], scol[4];
#pragma unroll
    for (int i = 0; i < 4; ++i) {
        int L = i * 4096 + tid * 16;
        int r = L >> 7;
        srow[i] = r;
        scol[i] = ((L & 127) ^ ((r & 7) << 4)) >> 1;
    }

    f32x4 acc[4][4];
#pragma unroll
    for (int mi = 0; mi < 4; ++mi)
#pragma unroll
        for (int ni = 0; ni < 4; ++ni)
            acc[mi][ni] = (f32x4){0.f, 0.f, 0.f, 0.f};

    const int wr = w >> 1, wc = w & 1;

    for (int kt = 0; kt < H_ / 64; ++kt) {
        const int k0 = kt * 64;
#pragma unroll
        for (int i = 0; i < 4; ++i) {
            async_copy16(Xbf + Xbase + (size_t)srow[i] * H_ + (k0 + scol[i]),
                         (char*)As + i * 4096 + w * 1024);
            async_copy16(Wbf + Wbase + (size_t)srow[i] * H_ + (k0 + scol[i]),
                         (char*)Bs + i * 4096 + w * 1024);
        }
        __syncthreads();

#pragma unroll
        for (int ks = 0; ks < 2; ++ks) {
            const int cb = ks * 64 + (lane >> 4) * 16;
            bf16x8 af[4], bfr[4];
#pragma unroll
            for (int mi = 0; mi < 4; ++mi) {
                int r = wr * 64 + mi * 16 + (lane & 15);
                af[mi] = *(const bf16x8*)((const char*)As + (r << 7) + (cb ^ ((r & 7) << 4)));
            }
#pragma unroll
            for (int ni = 0; ni < 4; ++ni) {
                int r = wc * 64 + ni * 16 + (lane & 15);
                bfr[ni] = *(const bf16x8*)((const char*)Bs + (r << 7) + (cb ^ ((r & 7) << 4)));
            }
#pragma unroll
            for (int mi = 0; mi < 4; ++mi)
#pragma unroll
                for (int ni = 0; ni < 4; ++ni)
                    acc[mi][ni] = __builtin_amdgcn_mfma_f32_16x16x32_bf16(af[mi], bfr[ni], acc[mi][ni], 0, 0, 0);
        }
        __syncthreads();
    }

    unsigned short* Td = T + (size_t)d * B_ * H_;
    const int row0 = tm * 128 + wr * 64;
    const int col0 = tn * 128 + wc * 64;
#pragma unroll
    for (int mi = 0; mi < 4; ++mi) {
#pragma unroll
        for (int j = 0; j < 4; ++j) {
            int r = row0 + mi * 16 + (lane >> 4) * 4 + j;
            unsigned short* dst = Td + (size_t)r * H_ + col0 + (lane & 15);
#pragma unroll
            for (int ni = 0; ni < 4; ++ni) {
                __half h = __float2half(acc[mi][ni][j]);
                dst[ni * 16] = *(unsigned short*)&h;
            }
        }
    }
}

// ---------------- K2: per-row norms + 10 pair dots on fp16 T ----------------
__global__ __launch_bounds__(256) void k2_scores(const unsigned short* __restrict__ T,
                                                 float* __restrict__ partials) {
    const int lane = threadIdx.x & 63;
    const int w    = threadIdx.x >> 6;
    const int gw   = blockIdx.x * 4 + w;  // 0..1023
    const size_t BH = (size_t)B_ * H_;

    float s[10];
#pragma unroll
    for (int p = 0; p < 10; ++p) s[p] = 0.f;

    for (int b = gw; b < B_; b += 1024) {
        const unsigned short* row = T + (size_t)b * H_;
        short8 u[4][2];
#pragma unroll
        for (int i = 0; i < 4; ++i) {
            u[i][0] = *(const short8*)(row + (size_t)i * BH + lane * 8);
            u[i][1] = *(const short8*)(row + (size_t)i * BH + 512 + lane * 8);
        }
        float dot[10];
#pragma unroll
        for (int p = 0; p < 10; ++p) dot[p] = 0.f;
#pragma unroll
        for (int h = 0; h < 2; ++h) {
#pragma unroll
            for (int e = 0; e < 8; ++e) {
                unsigned short c0 = (unsigned short)u[0][h][e];
                unsigned short c1 = (unsigned short)u[1][h][e];
                unsigned short c2 = (unsigned short)u[2][h][e];
                unsigned short c3 = (unsigned short)u[3][h][e];
                float f0 = __half2float(*(__half*)&c0);
                float f1 = __half2float(*(__half*)&c1);
                float f2v = __half2float(*(__half*)&c2);
                float f3 = __half2float(*(__half*)&c3);
                dot[0] += f0 * f0;  dot[1] += f0 * f1;  dot[2] += f0 * f2v; dot[3] += f0 * f3;
                dot[4] += f1 * f1;  dot[5] += f1 * f2v; dot[6] += f1 * f3;
                dot[7] += f2v * f2v; dot[8] += f2v * f3; dot[9] += f3 * f3;
            }
        }
#pragma unroll
        for (int p = 0; p < 10; ++p) {
            float v = dot[p];
#pragma unroll
            for (int m = 1; m < 64; m <<= 1) v += __shfl_xor(v, m, 64);
            dot[p] = v;
        }
        float i0 = rsqrtf(fmaxf(dot[0], 1e-24f));
        float i1 = rsqrtf(fmaxf(dot[4], 1e-24f));
        float i2 = rsqrtf(fmaxf(dot[7], 1e-24f));
        float i3 = rsqrtf(fmaxf(dot[9], 1e-24f));
        s[0] += dot[0] * i0 * i0;  s[1] += dot[1] * i0 * i1;
        s[2] += dot[2] * i0 * i2;  s[3] += dot[3] * i0 * i3;
        s[4] += dot[4] * i1 * i1;  s[5] += dot[5] * i1 * i2;
        s[6] += dot[6] * i1 * i3;  s[7] += dot[7] * i2 * i2;
        s[8] += dot[8] * i2 * i3;  s[9] += dot[9] * i3 * i3;
    }
    __shared__ float red[4][10];
    if (lane == 0) {
#pragma unroll
        for (int p = 0; p < 10; ++p) red[w][p] = s[p];
    }
    __syncthreads();
    if (threadIdx.x < 10)
        partials[blockIdx.x * 10 + threadIdx.x] =
            red[0][threadIdx.x] + red[1][threadIdx.x] + red[2][threadIdx.x] + red[3][threadIdx.x];
}

// ---------------- K2b: reduce partials, softmax -> attn[16] ----------------
__global__ void k2b_reduce(const float* __restrict__ partials, float* __restrict__ attn) {
    __shared__ float sums[10];
    int t = threadIdx.x;  // 64 threads
    if (t < 10) {
        float v = 0.f;
        for (int i = 0; i < 256; ++i) v += partials[i * 10 + t];
        sums[t] = v;
    }
    __syncthreads();
    if (t == 0) {
        const int pidx[4][4] = {{0, 1, 2, 3}, {1, 4, 5, 6}, {2, 5, 7, 8}, {3, 6, 8, 9}};
        for (int i = 0; i < 4; ++i) {
            float sc[4], m = -1e30f;
            for (int j = 0; j < 4; ++j) {
                sc[j] = sums[pidx[i][j]] * (1.0f / (float)B_);
                m = fmaxf(m, sc[j]);
            }
            float sum = 0.f;
            for (int j = 0; j < 4; ++j) { sc[j] = expf(sc[j] - m); sum += sc[j]; }
            for (int j = 0; j < 4; ++j) attn[i * 4 + j] = sc[j] / sum;
        }
    }
}

// ---------------- K3: out[d] = sum_g attn[d][g] * feats[g]  (pure fp32) ----------------
__global__ __launch_bounds__(256) void k3_out(const float* __restrict__ X,
                                              const float* __restrict__ attn,
                                              float* __restrict__ out) {
    float a[16];
#pragma unroll
    for (int i = 0; i < 16; ++i) a[i] = attn[i];
    const size_t BH = (size_t)B_ * H_;
    const size_t nv = BH / 4;
    for (size_t p = (size_t)blockIdx.x * 256 + threadIdx.x; p < nv;
         p += (size_t)gridDim.x * 256) {
        f32x4 g0 = *(const f32x4*)(X + p * 4);
        f32x4 g1 = *(const f32x4*)(X + BH + p * 4);
        f32x4 g2 = *(const f32x4*)(X + 2 * BH + p * 4);
        f32x4 g3 = *(const f32x4*)(X + 3 * BH + p * 4);
        f32x4 o0, o1, o2, o3;
#pragma unroll
        for (int e = 0; e < 4; ++e) {
            o0[e] = a[0]  * g0[e] + a[1]  * g1[e] + a[2]  * g2[e] + a[3]  * g3[e];
            o1[e] = a[4]  * g0[e] + a[5]  * g1[e] + a[6]  * g2[e] + a[7]  * g3[e];
            o2[e] = a[8]  * g0[e] + a[9]  * g1[e] + a[10] * g2[e] + a[11] * g3[e];
            o3[e] = a[12] * g0[e] + a[13] * g1[e] + a[14] * g2[e] + a[15] * g3[e];
        }
        *(f32x4*)(out + p * 4) = o0;
        *(f32x4*)(out + BH + p * 4) = o1;
        *(f32x4*)(out + 2 * BH + p * 4) = o2;
        *(f32x4*)(out + 3 * BH + p * 4) = o3;
    }
}

extern "C" void kernel_launch(void* const* d_in, const int* in_sizes, int n_in,
                              void* d_out, int out_size, void* d_ws, size_t ws_size,
                              hipStream_t stream) {
    (void)in_sizes; (void)n_in; (void)out_size;
    const float* feats   = (const float*)d_in[0];   // fp32 [4][16384][1024]
    const float* weights = (const float*)d_in[1];   // fp32 [4][1024][1024]
    float* out = (float*)d_out;

    // d_out during pipeline: [T fp16: 134.2MB][Xbf bf16: 134.2MB]
    const size_t half_bytes = (size_t)D_ * B_ * H_ * 2;
    unsigned short* T   = (unsigned short*)d_out;
    unsigned short* Xbf = (unsigned short*)((char*)d_out + half_bytes);

    float* attn     = (float*)d_ws;                      // 16 floats @ 0
    float* partials = (float*)((char*)d_ws + 256);       // 256*10 floats
    const size_t WBF_OFF   = 65536;
    const size_t WBF_BYTES = (size_t)D_ * H_ * H_ * 2;   // 8.39 MB
    unsigned short* Wbf = (unsigned short*)((char*)d_ws + WBF_OFF);
    const bool use_ws = ws_size >= WBF_OFF + WBF_BYTES;  // fixed -> deterministic

    k0_cvt<<<2048, 256, 0, stream>>>(feats, Xbf);
    if (use_ws) {
        k0b_cvt<<<512, 256, 0, stream>>>(weights, Wbf);
        k1_gemm8<<<1024, 512, 0, stream>>>(Xbf, Wbf, T);
    } else {
        // no ws for Wbf: fall back to staging... (never expected; keeps determinism)
        k1_gemm_bf<<<4096, 256, 0, stream>>>(Xbf, (const unsigned short*)weights, T);
    }
    k2_scores<<<256, 256, 0, stream>>>(T, partials);
    k2b_reduce<<<1, 64, 0, stream>>>(partials, attn);
    k3_out<<<2048, 256, 0, stream>>>(feats, attn, out);
}

// Round 5
// 340.991 us; speedup vs baseline: 1.3231x; 1.0336x over previous
//
#include <hip/hip_runtime.h>
#include <hip/hip_bf16.h>
#include <hip/hip_fp16.h>
#include <stdint.h>

#define D_ 4
#define B_ 16384
#define H_ 1024

typedef __attribute__((ext_vector_type(8))) __bf16 bf16x8;
typedef __attribute__((ext_vector_type(8))) short short8;
typedef __attribute__((ext_vector_type(4))) float f32x4;

typedef __attribute__((address_space(1))) void gvoid_t;
typedef __attribute__((address_space(3))) void lvoid_t;

__device__ __forceinline__ void async_copy16(const void* g, void* l) {
    __builtin_amdgcn_global_load_lds((const gvoid_t*)g, (lvoid_t*)l, 16, 0, 0);
}

__device__ __forceinline__ unsigned short f2b(float f) {  // fp32 -> bf16 bits, RNE
    union { float f; uint32_t i; } v; v.f = f;
    uint32_t r = v.i + 0x7fffu + ((v.i >> 16) & 1u);
    return (unsigned short)(r >> 16);
}
__device__ __forceinline__ float b2f(unsigned short u) {
    union { uint32_t i; float f; } v; v.i = ((uint32_t)u) << 16; return v.f;
}

// ---------------- K0: feats fp32 -> bf16 (Xbf) ----------------
__global__ __launch_bounds__(256) void k0_cvt(const float* __restrict__ X,
                                              unsigned short* __restrict__ Xbf) {
    const size_t n8 = (size_t)D_ * B_ * H_ / 8;
    for (size_t p = (size_t)blockIdx.x * 256 + threadIdx.x; p < n8;
         p += (size_t)gridDim.x * 256) {
        f32x4 a = *(const f32x4*)(X + p * 8);
        f32x4 b = *(const f32x4*)(X + p * 8 + 4);
        short8 o;
        o[0] = (short)f2b(a[0]); o[1] = (short)f2b(a[1]);
        o[2] = (short)f2b(a[2]); o[3] = (short)f2b(a[3]);
        o[4] = (short)f2b(b[0]); o[5] = (short)f2b(b[1]);
        o[6] = (short)f2b(b[2]); o[7] = (short)f2b(b[3]);
        *(short8*)(Xbf + p * 8) = o;
    }
}

// ---------------- K0b: weights fp32 -> bf16 (Wbf) ----------------
__global__ __launch_bounds__(256) void k0b_cvt(const float* __restrict__ W,
                                               unsigned short* __restrict__ Wbf) {
    const size_t n8 = (size_t)D_ * H_ * H_ / 8;
    for (size_t p = (size_t)blockIdx.x * 256 + threadIdx.x; p < n8;
         p += (size_t)gridDim.x * 256) {
        f32x4 a = *(const f32x4*)(W + p * 8);
        f32x4 b = *(const f32x4*)(W + p * 8 + 4);
        short8 o;
        o[0] = (short)f2b(a[0]); o[1] = (short)f2b(a[1]);
        o[2] = (short)f2b(a[2]); o[3] = (short)f2b(a[3]);
        o[4] = (short)f2b(b[0]); o[5] = (short)f2b(b[1]);
        o[6] = (short)f2b(b[2]); o[7] = (short)f2b(b[3]);
        *(short8*)(Wbf + p * 8) = o;
    }
}

// ============ K1: 256x256x64 6-phase double-buffered bf16 GEMM ============
// 8 waves (2M x 4N), per-wave 128x64 = acc[8][4] f32x4. LDS 128KB, XOR swizzle.
// vmcnt(4) BEFORE the closing barrier of merged phases (all-waves DMA guarantee).
__global__ __launch_bounds__(512, 2) void k1_gemm8(const unsigned short* __restrict__ Xbf,
                                                   const unsigned short* __restrict__ Wbf,
                                                   unsigned short* __restrict__ T) {
    __shared__ __align__(16) unsigned short lds[4][256 * 64];  // 128 KB

    const int tid  = threadIdx.x;
    const int lane = tid & 63;
    const int w    = tid >> 6;   // 0..7
    const int wr   = w >> 2;     // 0..1
    const int wc   = w & 3;      // 0..3

    // XCD-aware bijective swizzle: 1024 blocks, 128 per XCD
    const int bid0 = blockIdx.x;
    const int bid  = (bid0 & 7) * 128 + (bid0 >> 3);
    const int d    = bid >> 8;
    const int t    = bid & 255;
    const int tn   = t & 3;
    const int tm   = t >> 2;

    const size_t Xbase = ((size_t)d * B_ + (size_t)tm * 256) * H_;
    const size_t Wbase = ((size_t)d * H_ + (size_t)tn * 256) * H_;

    const unsigned short* aSrc[2][2];
    const unsigned short* bSrc[2][2];
#pragma unroll
    for (int h = 0; h < 2; ++h)
#pragma unroll
        for (int c = 0; c < 2; ++c) {
            int L = h * 16384 + c * 8192 + tid * 16;
            int r = L >> 7;
            int col = ((L & 127) ^ ((r & 7) << 4)) >> 1;
            aSrc[h][c] = Xbf + Xbase + (size_t)r * H_ + col;
            bSrc[h][c] = Wbf + Wbase + (size_t)r * H_ + col;
        }

    char* ldsB = (char*)&lds[0][0];

    auto stageA = [&](int buf, int h, int kt) {
#pragma unroll
        for (int c = 0; c < 2; ++c)
            async_copy16(aSrc[h][c] + kt * 64,
                         ldsB + (buf * 2 + 0) * 32768 + h * 16384 + c * 8192 + w * 1024);
    };
    auto stageB = [&](int buf, int h, int kt) {
#pragma unroll
        for (int c = 0; c < 2; ++c)
            async_copy16(bSrc[h][c] + kt * 64,
                         ldsB + (buf * 2 + 1) * 32768 + h * 16384 + c * 8192 + w * 1024);
    };

    bf16x8 ar[4][2], b0[2][2], b1[2][2];
    const int rA15 = lane & 15;
    const int cB16 = (lane >> 4) * 16;

    auto readA = [&](int buf, int mib) {
#pragma unroll
        for (int mi = 0; mi < 4; ++mi) {
            int r = wr * 128 + mib + mi * 16 + rA15;
            const char* base = ldsB + (buf * 2 + 0) * 32768 + (r << 7);
            int sw = (r & 7) << 4;
#pragma unroll
            for (int ks = 0; ks < 2; ++ks)
                ar[mi][ks] = *(const bf16x8*)(base + ((ks * 64 + cB16) ^ sw));
        }
    };
    auto readB0 = [&](int buf) {
#pragma unroll
        for (int ni = 0; ni < 2; ++ni) {
            int r = wc * 64 + ni * 16 + rA15;
            const char* base = ldsB + (buf * 2 + 1) * 32768 + (r << 7);
            int sw = (r & 7) << 4;
#pragma unroll
            for (int ks = 0; ks < 2; ++ks)
                b0[ni][ks] = *(const bf16x8*)(base + ((ks * 64 + cB16) ^ sw));
        }
    };
    auto readB1 = [&](int buf) {
#pragma unroll
        for (int ni = 0; ni < 2; ++ni) {
            int r = wc * 64 + 32 + ni * 16 + rA15;
            const char* base = ldsB + (buf * 2 + 1) * 32768 + (r << 7);
            int sw = (r & 7) << 4;
#pragma unroll
            for (int ks = 0; ks < 2; ++ks)
                b1[ni][ks] = *(const bf16x8*)(base + ((ks * 64 + cB16) ^ sw));
        }
    };

    f32x4 acc[8][4];
#pragma unroll
    for (int a = 0; a < 8; ++a)
#pragma unroll
        for (int n = 0; n < 4; ++n) acc[a][n] = (f32x4){0.f, 0.f, 0.f, 0.f};

#define VMCNT4 do { asm volatile("s_waitcnt vmcnt(4)" ::: "memory"); \
                    __builtin_amdgcn_sched_barrier(0); } while (0)
#define LGKM0  do { asm volatile("s_waitcnt lgkmcnt(0)" ::: "memory"); \
                    __builtin_amdgcn_sched_barrier(0); } while (0)
#define BAR    __builtin_amdgcn_s_barrier()

#define MFMA16NP(AOFF, BB, NOFF)                                                             \
    do {                                                                                     \
        _Pragma("unroll")                                                                    \
        for (int ks = 0; ks < 2; ++ks)                                                       \
            _Pragma("unroll")                                                                \
            for (int mi = 0; mi < 4; ++mi)                                                   \
                _Pragma("unroll")                                                            \
                for (int ni = 0; ni < 2; ++ni)                                               \
                    acc[(AOFF) + mi][(NOFF) + ni] = __builtin_amdgcn_mfma_f32_16x16x32_bf16( \
                        ar[mi][ks], ((BB)[ni][ks]), acc[(AOFF) + mi][(NOFF) + ni], 0, 0, 0); \
    } while (0)
#define MFMA16(AOFF, BB, NOFF)                     \
    do {                                           \
        __builtin_amdgcn_s_setprio(1);             \
        MFMA16NP(AOFF, BB, NOFF);                  \
        __builtin_amdgcn_s_setprio(0);             \
    } while (0)

    // Prologue: buf0 <- K-tile 0 (A+B), buf1 <- B of K-tile 1.  12 loads.
    stageA(0, 0, 0); stageA(0, 1, 0); stageB(0, 0, 0); stageB(0, 1, 0);
    stageB(1, 0, 1); stageB(1, 1, 1);
    VMCNT4;  // confirm buf0 (8 oldest); leave B(buf1) in flight
    BAR;     // all waves' buf0 confirmed -> safe to read others' chunks

    for (int it = 0; it < 8; ++it) {
        const int ka  = 2 * it + 1;
        const int kb2 = (2 * it + 2) & 15;  // wraps harmlessly on last iter
        const int kb3 = (2 * it + 3) & 15;

        // P1: q(r0,c0) buf0
        readA(0, 0); readB0(0);
        stageA(1, 0, ka);                     // S1
        BAR; LGKM0;
        MFMA16(0, b0, 0);
        BAR;
        // P2: q(r0,c1) buf0
        readB1(0);
        stageA(1, 1, ka);                     // S2
        BAR; LGKM0;
        MFMA16(0, b1, 2);
        BAR;
        // P3 (merged): q(r1,c1)+q(r1,c0) buf0
        readA(0, 64);
        stageB(0, 0, kb2); stageB(0, 1, kb2); // S3,S4 (buf0-B reads done at P2)
        BAR; LGKM0;
        __builtin_amdgcn_s_setprio(1);
        MFMA16NP(4, b1, 2);
        MFMA16NP(4, b0, 0);
        __builtin_amdgcn_s_setprio(0);
        VMCNT4;  // confirm prev B(buf1)+S1+S2 -> buf1 complete after BAR
        BAR;
        // P4: q(r0,c0) buf1
        readA(1, 0); readB0(1);
        stageA(0, 0, kb2);                    // S5 (buf0-A reads done at P3)
        BAR; LGKM0;
        MFMA16(0, b0, 0);
        BAR;
        // P5: q(r0,c1) buf1
        readB1(1);
        stageA(0, 1, kb2);                    // S6
        BAR; LGKM0;
        MFMA16(0, b1, 2);
        BAR;
        // P6 (merged): q(r1,c1)+q(r1,c0) buf1
        readA(1, 64);
        stageB(1, 0, kb3); stageB(1, 1, kb3); // S7,S8
        BAR; LGKM0;
        __builtin_amdgcn_s_setprio(1);
        MFMA16NP(4, b1, 2);
        MFMA16NP(4, b0, 0);
        __builtin_amdgcn_s_setprio(0);
        VMCNT4;  // confirm S3..S6 -> buf0 complete after BAR
        BAR;
    }

#undef VMCNT4
#undef LGKM0
#undef BAR
#undef MFMA16
#undef MFMA16NP

    // Epilogue: C/D layout col=lane&15, row=(lane>>4)*4+j; T stored fp16
    unsigned short* Td = T + (size_t)d * B_ * H_;
    const int row0 = tm * 256 + wr * 128;
    const int col0 = tn * 256 + wc * 64 + (lane & 15);
#pragma unroll
    for (int a = 0; a < 8; ++a) {
#pragma unroll
        for (int j = 0; j < 4; ++j) {
            int r = row0 + a * 16 + (lane >> 4) * 4 + j;
            unsigned short* dst = Td + (size_t)r * H_ + col0;
#pragma unroll
            for (int ni = 0; ni < 4; ++ni) {
                __half h = __float2half(acc[a][ni][j]);
                dst[ni * 16] = *(unsigned short*)&h;
            }
        }
    }
}

// ---------------- K2: per-row norms + 10 pair dots on fp16 T ----------------
__global__ __launch_bounds__(256) void k2_scores(const unsigned short* __restrict__ T,
                                                 float* __restrict__ partials) {
    const int lane = threadIdx.x & 63;
    const int w    = threadIdx.x >> 6;
    const int gw   = blockIdx.x * 4 + w;
    const size_t BH = (size_t)B_ * H_;

    float s[10];
#pragma unroll
    for (int p = 0; p < 10; ++p) s[p] = 0.f;

    for (int b = gw; b < B_; b += 1024) {
        const unsigned short* row = T + (size_t)b * H_;
        short8 u[4][2];
#pragma unroll
        for (int i = 0; i < 4; ++i) {
            u[i][0] = *(const short8*)(row + (size_t)i * BH + lane * 8);
            u[i][1] = *(const short8*)(row + (size_t)i * BH + 512 + lane * 8);
        }
        float dot[10];
#pragma unroll
        for (int p = 0; p < 10; ++p) dot[p] = 0.f;
#pragma unroll
        for (int h = 0; h < 2; ++h) {
#pragma unroll
            for (int e = 0; e < 8; ++e) {
                unsigned short c0 = (unsigned short)u[0][h][e];
                unsigned short c1 = (unsigned short)u[1][h][e];
                unsigned short c2 = (unsigned short)u[2][h][e];
                unsigned short c3 = (unsigned short)u[3][h][e];
                float f0 = __half2float(*(__half*)&c0);
                float f1 = __half2float(*(__half*)&c1);
                float f2v = __half2float(*(__half*)&c2);
                float f3 = __half2float(*(__half*)&c3);
                dot[0] += f0 * f0;  dot[1] += f0 * f1;  dot[2] += f0 * f2v; dot[3] += f0 * f3;
                dot[4] += f1 * f1;  dot[5] += f1 * f2v; dot[6] += f1 * f3;
                dot[7] += f2v * f2v; dot[8] += f2v * f3; dot[9] += f3 * f3;
            }
        }
#pragma unroll
        for (int p = 0; p < 10; ++p) {
            float v = dot[p];
#pragma unroll
            for (int m = 1; m < 64; m <<= 1) v += __shfl_xor(v, m, 64);
            dot[p] = v;
        }
        float i0 = rsqrtf(fmaxf(dot[0], 1e-24f));
        float i1 = rsqrtf(fmaxf(dot[4], 1e-24f));
        float i2 = rsqrtf(fmaxf(dot[7], 1e-24f));
        float i3 = rsqrtf(fmaxf(dot[9], 1e-24f));
        s[0] += dot[0] * i0 * i0;  s[1] += dot[1] * i0 * i1;
        s[2] += dot[2] * i0 * i2;  s[3] += dot[3] * i0 * i3;
        s[4] += dot[4] * i1 * i1;  s[5] += dot[5] * i1 * i2;
        s[6] += dot[6] * i1 * i3;  s[7] += dot[7] * i2 * i2;
        s[8] += dot[8] * i2 * i3;  s[9] += dot[9] * i3 * i3;
    }
    __shared__ float red[4][10];
    if (lane == 0) {
#pragma unroll
        for (int p = 0; p < 10; ++p) red[w][p] = s[p];
    }
    __syncthreads();
    if (threadIdx.x < 10)
        partials[blockIdx.x * 10 + threadIdx.x] =
            red[0][threadIdx.x] + red[1][threadIdx.x] + red[2][threadIdx.x] + red[3][threadIdx.x];
}

// ---------------- K2b: reduce partials, softmax -> attn[16] ----------------
__global__ void k2b_reduce(const float* __restrict__ partials, float* __restrict__ attn) {
    __shared__ float sums[10];
    int t = threadIdx.x;
    if (t < 10) {
        float v = 0.f;
        for (int i = 0; i < 256; ++i) v += partials[i * 10 + t];
        sums[t] = v;
    }
    __syncthreads();
    if (t == 0) {
        const int pidx[4][4] = {{0, 1, 2, 3}, {1, 4, 5, 6}, {2, 5, 7, 8}, {3, 6, 8, 9}};
        for (int i = 0; i < 4; ++i) {
            float sc[4], m = -1e30f;
            for (int j = 0; j < 4; ++j) {
                sc[j] = sums[pidx[i][j]] * (1.0f / (float)B_);
                m = fmaxf(m, sc[j]);
            }
            float sum = 0.f;
            for (int j = 0; j < 4; ++j) { sc[j] = expf(sc[j] - m); sum += sc[j]; }
            for (int j = 0; j < 4; ++j) attn[i * 4 + j] = sc[j] / sum;
        }
    }
}

// ---------------- K3 (primary): out = attn @ Xbf (bf16 reads, fp32 out) ----------------
__global__ __launch_bounds__(256) void k3_out_bf(const unsigned short* __restrict__ Xbf,
                                                 const float* __restrict__ attn,
                                                 float* __restrict__ out) {
    float a[16];
#pragma unroll
    for (int i = 0; i < 16; ++i) a[i] = attn[i];
    const size_t BH = (size_t)B_ * H_;
    const size_t nv = BH / 8;
    for (size_t p = (size_t)blockIdx.x * 256 + threadIdx.x; p < nv;
         p += (size_t)gridDim.x * 256) {
        short8 f0 = *(const short8*)(Xbf + p * 8);
        short8 f1 = *(const short8*)(Xbf + BH + p * 8);
        short8 f2v = *(const short8*)(Xbf + 2 * BH + p * 8);
        short8 f3 = *(const short8*)(Xbf + 3 * BH + p * 8);
        float o0[8], o1[8], o2[8], o3[8];
#pragma unroll
        for (int e = 0; e < 8; ++e) {
            float g0 = b2f((unsigned short)f0[e]);
            float g1 = b2f((unsigned short)f1[e]);
            float g2 = b2f((unsigned short)f2v[e]);
            float g3 = b2f((unsigned short)f3[e]);
            o0[e] = a[0]  * g0 + a[1]  * g1 + a[2]  * g2 + a[3]  * g3;
            o1[e] = a[4]  * g0 + a[5]  * g1 + a[6]  * g2 + a[7]  * g3;
            o2[e] = a[8]  * g0 + a[9]  * g1 + a[10] * g2 + a[11] * g3;
            o3[e] = a[12] * g0 + a[13] * g1 + a[14] * g2 + a[15] * g3;
        }
#pragma unroll
        for (int h = 0; h < 2; ++h) {
            *(f32x4*)(out + p * 8 + h * 4)           = (f32x4){o0[h*4], o0[h*4+1], o0[h*4+2], o0[h*4+3]};
            *(f32x4*)(out + BH + p * 8 + h * 4)      = (f32x4){o1[h*4], o1[h*4+1], o1[h*4+2], o1[h*4+3]};
            *(f32x4*)(out + 2 * BH + p * 8 + h * 4)  = (f32x4){o2[h*4], o2[h*4+1], o2[h*4+2], o2[h*4+3]};
            *(f32x4*)(out + 3 * BH + p * 8 + h * 4)  = (f32x4){o3[h*4], o3[h*4+1], o3[h*4+2], o3[h*4+3]};
        }
    }
}

// ---------------- K3 (fallback): pure fp32 ----------------
__global__ __launch_bounds__(256) void k3_out(const float* __restrict__ X,
                                              const float* __restrict__ attn,
                                              float* __restrict__ out) {
    float a[16];
#pragma unroll
    for (int i = 0; i < 16; ++i) a[i] = attn[i];
    const size_t BH = (size_t)B_ * H_;
    const size_t nv = BH / 4;
    for (size_t p = (size_t)blockIdx.x * 256 + threadIdx.x; p < nv;
         p += (size_t)gridDim.x * 256) {
        f32x4 g0 = *(const f32x4*)(X + p * 4);
        f32x4 g1 = *(const f32x4*)(X + BH + p * 4);
        f32x4 g2 = *(const f32x4*)(X + 2 * BH + p * 4);
        f32x4 g3 = *(const f32x4*)(X + 3 * BH + p * 4);
        f32x4 o0, o1, o2, o3;
#pragma unroll
        for (int e = 0; e < 4; ++e) {
            o0[e] = a[0]  * g0[e] + a[1]  * g1[e] + a[2]  * g2[e] + a[3]  * g3[e];
            o1[e] = a[4]  * g0[e] + a[5]  * g1[e] + a[6]  * g2[e] + a[7]  * g3[e];
            o2[e] = a[8]  * g0[e] + a[9]  * g1[e] + a[10] * g2[e] + a[11] * g3[e];
            o3[e] = a[12] * g0[e] + a[13] * g1[e] + a[14] * g2[e] + a[15] * g3[e];
        }
        *(f32x4*)(out + p * 4) = o0;
        *(f32x4*)(out + BH + p * 4) = o1;
        *(f32x4*)(out + 2 * BH + p * 4) = o2;
        *(f32x4*)(out + 3 * BH + p * 4) = o3;
    }
}

extern "C" void kernel_launch(void* const* d_in, const int* in_sizes, int n_in,
                              void* d_out, int out_size, void* d_ws, size_t ws_size,
                              hipStream_t stream) {
    (void)in_sizes; (void)n_in; (void)out_size;
    const float* feats   = (const float*)d_in[0];   // fp32 [4][16384][1024]
    const float* weights = (const float*)d_in[1];   // fp32 [4][1024][1024]
    float* out = (float*)d_out;

    float* attn     = (float*)d_ws;                      // 16 floats @ 0
    float* partials = (float*)((char*)d_ws + 256);       // 256*10 floats
    const size_t WBF_OFF   = 65536;
    const size_t WBF_BYTES = (size_t)D_ * H_ * H_ * 2;   // 8.39 MB
    const size_t XBF_OFF   = WBF_OFF + WBF_BYTES;        // 8,454,144 (16B aligned)
    const size_t XBF_BYTES = (size_t)D_ * B_ * H_ * 2;   // 134.2 MB
    unsigned short* Wbf = (unsigned short*)((char*)d_ws + WBF_OFF);

    const bool big_ws = ws_size >= XBF_OFF + XBF_BYTES;  // ~142.7 MB
    const bool med_ws = ws_size >= WBF_OFF + WBF_BYTES;  // ~8.45 MB

    const size_t half_bytes = (size_t)D_ * B_ * H_ * 2;
    unsigned short* T = (unsigned short*)d_out;          // T fp16 in d_out first half

    if (big_ws) {
        unsigned short* Xbf = (unsigned short*)((char*)d_ws + XBF_OFF);
        k0_cvt<<<2048, 256, 0, stream>>>(feats, Xbf);
        k0b_cvt<<<512, 256, 0, stream>>>(weights, Wbf);
        k1_gemm8<<<1024, 512, 0, stream>>>(Xbf, Wbf, T);
        k2_scores<<<256, 256, 0, stream>>>(T, partials);
        k2b_reduce<<<1, 64, 0, stream>>>(partials, attn);
        k3_out_bf<<<2048, 256, 0, stream>>>(Xbf, attn, out);
    } else if (med_ws) {
        unsigned short* Xbf = (unsigned short*)((char*)d_out + half_bytes);
        k0_cvt<<<2048, 256, 0, stream>>>(feats, Xbf);
        k0b_cvt<<<512, 256, 0, stream>>>(weights, Wbf);
        k1_gemm8<<<1024, 512, 0, stream>>>(Xbf, Wbf, T);
        k2_scores<<<256, 256, 0, stream>>>(T, partials);
        k2b_reduce<<<1, 64, 0, stream>>>(partials, attn);
        k3_out<<<2048, 256, 0, stream>>>(feats, attn, out);
    }
}